// Round 1
// baseline (94.056 us; speedup 1.0000x reference)
//
#include <hip/hip_runtime.h>

// Problem constants (from reference): x[C=64][H=512][W=512] fp32,
// out[C=64][OH=256][OW=256] fp32. 2x2 stride-2 window, MaxNetwork math:
//   pairmax(a,b) = relu(relu(a-b) + relu(b)) = max(a-b,0) + max(b,0)
// (both terms non-negative, so outer relu is identity).
// Window element order: (0,0),(0,1),(1,0),(1,1);
//   m1 = pairmax(w00, w01); m2 = pairmax(w10, w11); out = pairmax(m1, m2).

#define C_  64
#define H_  512
#define W_  512
#define OH_ 256
#define OW_ 256

__device__ __forceinline__ float pairmax(float a, float b) {
    return fmaxf(a - b, 0.0f) + fmaxf(b, 0.0f);
}

// One thread -> 2 output pixels (one 2x2 window pair).
// Loads: 2x float4 (16B/lane, fully coalesced). Store: 1x float2 (8B/lane).
__global__ __launch_bounds__(256) void maxnet_pool_kernel(
        const float* __restrict__ x, float* __restrict__ out) {
    const int tid = blockIdx.x * blockDim.x + threadIdx.x; // [0, C*OH*OW/2)
    const int ow2  = tid & (OW_ / 2 - 1);   // which pair of output cols (0..127)
    const int rest = tid >> 7;              // c*OH + oh
    // Input row for this output row: c*H + 2*oh = 2*(c*OH + oh) = 2*rest.
    const int base = (rest << 1) * W_ + (ow2 << 2);  // 16B-aligned float offset

    const float4 r0 = *reinterpret_cast<const float4*>(x + base);        // row 2*oh
    const float4 r1 = *reinterpret_cast<const float4*>(x + base + W_);   // row 2*oh+1

    // Window 0: cols {0,1}; window 1: cols {2,3}
    float2 o;
    {
        const float m1 = pairmax(r0.x, r0.y);
        const float m2 = pairmax(r1.x, r1.y);
        o.x = pairmax(m1, m2);
    }
    {
        const float m1 = pairmax(r0.z, r0.w);
        const float m2 = pairmax(r1.z, r1.w);
        o.y = pairmax(m1, m2);
    }
    *reinterpret_cast<float2*>(out + (tid << 1)) = o;
}

extern "C" void kernel_launch(void* const* d_in, const int* in_sizes, int n_in,
                              void* d_out, int out_size, void* d_ws, size_t ws_size,
                              hipStream_t stream) {
    const float* x = (const float*)d_in[0];
    float* out = (float*)d_out;
    const int n_threads = C_ * OH_ * (OW_ / 2);  // 2,097,152
    const int block = 256;
    const int grid = n_threads / block;          // 8192
    maxnet_pool_kernel<<<grid, block, 0, stream>>>(x, out);
}